// Round 5
// baseline (281.316 us; speedup 1.0000x reference)
//
#include <hip/hip_runtime.h>

#define BB 4096
#define TT 512
#define HH 10

__device__ __forceinline__ float fast_rcp(float x) { return __builtin_amdgcn_rcpf(x); }
__device__ __forceinline__ float sigm(float z) { return fast_rcp(1.0f + __expf(-z)); }
// tanh(z) = 2*sigmoid(2z) - 1
__device__ __forceinline__ float tanh_(float z) { return 2.0f * sigm(2.0f * z) - 1.0f; }

// DPP quad_perm: CTRL = q0 | q1<<2 | q2<<4 | q3<<6. VALU-pipe cross-lane, ~4cy latency.
template <int CTRL>
__device__ __forceinline__ float dpp_qperm(float v) {
    return __int_as_float(__builtin_amdgcn_update_dpp(
        0, __float_as_int(v), CTRL, 0xf, 0xf, true));
}
#define BCAST0 0x00
#define BCAST1 0x55
#define BCAST2 0xAA
#define BCAST3 0xFF
#define XOR1   0xB1  // [1,0,3,2]
#define XOR2   0x4E  // [2,3,0,1]

// Pin a value into a VGPR and make it opaque: the compiler can no longer
// rematerialize/sink the load that produced it, so it must stay register-resident.
#define PIN(v) asm volatile("" : "+v"(v))

// 4 lanes per batch element. Lane q owns hidden units u = q + 4k (3/3/2/2).
// All weights pinned in registers; h exchanged across the quad with DPP quad_perm.
__global__ __launch_bounds__(64, 1)
__attribute__((amdgpu_waves_per_eu(1, 1)))
void lstm_quad_dpp_kernel(
    const float* __restrict__ x, const float* __restrict__ h0, const float* __restrict__ c0,
    const float* __restrict__ W_ih, const float* __restrict__ W_hh,
    const float* __restrict__ b_ih, const float* __restrict__ b_hh,
    const float* __restrict__ W1, const float* __restrict__ b1,
    const float* __restrict__ W2, const float* __restrict__ b2,
    float* __restrict__ out)
{
    const int lane = threadIdx.x;                  // block = 64 = one wave
    const int q = lane & 3;
    const int e = (blockIdx.x * 64 + lane) >> 2;   // batch element, 16 per wave

    // ---- per-lane register weights ----
    float W[3][4][10];      // [k][gate][j]  (gate order i,f,g,o)
    float wih[3][4], bsum[3][4];
    float W1r[3][10], b1r[3], W2r[3];

#pragma unroll
    for (int k = 0; k < 3; k++) {
        const int u = q + 4 * k;
        const bool valid = (u < HH);
        const float m = valid ? 1.0f : 0.0f;
        const int uu = valid ? u : 0;
#pragma unroll
        for (int g = 0; g < 4; g++) {
            const int row = g * HH + uu;
            const float2* rp = (const float2*)(W_hh + row * HH);
#pragma unroll
            for (int jj = 0; jj < 5; jj++) {
                float2 w = rp[jj];
                W[k][g][2 * jj]     = w.x * m;
                W[k][g][2 * jj + 1] = w.y * m;
            }
            wih[k][g]  = W_ih[row] * m;
            bsum[k][g] = (b_ih[row] + b_hh[row]) * m;
        }
        const float2* r1 = (const float2*)(W1 + uu * HH);
#pragma unroll
        for (int jj = 0; jj < 5; jj++) {
            float2 w = r1[jj];
            W1r[k][2 * jj]     = w.x * m;
            W1r[k][2 * jj + 1] = w.y * m;
        }
        b1r[k] = b1[uu] * m;
        W2r[k] = W2[uu] * m;
    }
    float b2s = b2[0];

    // ---- force every weight to be register-resident (non-rematerializable) ----
#pragma unroll
    for (int k = 0; k < 3; k++) {
#pragma unroll
        for (int g = 0; g < 4; g++) {
            PIN(wih[k][g]);
            PIN(bsum[k][g]);
#pragma unroll
            for (int j = 0; j < 10; j++) PIN(W[k][g][j]);
        }
#pragma unroll
        for (int j = 0; j < 10; j++) PIN(W1r[k][j]);
        PIN(b1r[k]);
        PIN(W2r[k]);
    }
    PIN(b2s);

    // ---- state ----
    float h[10], c[3];
#pragma unroll
    for (int j = 0; j < 10; j++) h[j] = h0[e * HH + j];
#pragma unroll
    for (int k = 0; k < 3; k++) {
        const int u = q + 4 * k;
        c[k] = (u < HH) ? c0[e * HH + u] : 0.0f;
    }

    const float4* xq  = (const float4*)(x + (size_t)e * TT);
    float4*       ob4 = (float4*)(out + (size_t)e * TT);

    float4 xc = xq[0];
    for (int gb = 0; gb < TT / 4; gb++) {
        float4 xn = xq[(gb + 1 < TT / 4) ? gb + 1 : gb];
        float4 outv;

#pragma unroll
        for (int r = 0; r < 4; r++) {
            const float xv = (r == 0) ? xc.x : (r == 1) ? xc.y : (r == 2) ? xc.z : xc.w;

            // ---- own gates + state update ----
            float hn[3];
#pragma unroll
            for (int k = 0; k < 3; k++) {
                float g0 = fmaf(xv, wih[k][0], bsum[k][0]);
                float g1 = fmaf(xv, wih[k][1], bsum[k][1]);
                float g2 = fmaf(xv, wih[k][2], bsum[k][2]);
                float g3 = fmaf(xv, wih[k][3], bsum[k][3]);
#pragma unroll
                for (int j = 0; j < 10; j++) {
                    const float hj = h[j];
                    g0 = fmaf(hj, W[k][0][j], g0);
                    g1 = fmaf(hj, W[k][1][j], g1);
                    g2 = fmaf(hj, W[k][2][j], g2);
                    g3 = fmaf(hj, W[k][3][j], g3);
                }
                const float iv = sigm(g0);
                const float fv = sigm(g1);
                const float gv = tanh_(g2);
                const float ov = sigm(g3);
                const float cn = fmaf(fv, c[k], iv * gv);
                c[k] = cn;
                hn[k] = ov * tanh_(cn);
            }

            // ---- broadcast h across the quad: DPP quad_perm (VALU pipe, no LDS) ----
            h[0] = dpp_qperm<BCAST0>(hn[0]);
            h[1] = dpp_qperm<BCAST1>(hn[0]);
            h[2] = dpp_qperm<BCAST2>(hn[0]);
            h[3] = dpp_qperm<BCAST3>(hn[0]);
            h[4] = dpp_qperm<BCAST0>(hn[1]);
            h[5] = dpp_qperm<BCAST1>(hn[1]);
            h[6] = dpp_qperm<BCAST2>(hn[1]);
            h[7] = dpp_qperm<BCAST3>(hn[1]);
            h[8] = dpp_qperm<BCAST0>(hn[2]);
            h[9] = dpp_qperm<BCAST1>(hn[2]);

            // ---- regressor partial: relu(W1 h + b1) . W2 over owned units ----
            float sp = 0.0f;
#pragma unroll
            for (int k = 0; k < 3; k++) {
                float acc = b1r[k];
#pragma unroll
                for (int j = 0; j < 10; j++) acc = fmaf(h[j], W1r[k][j], acc);
                sp = fmaf(fmaxf(acc, 0.0f), W2r[k], sp);
            }
            // quad reduction on the VALU pipe
            sp += dpp_qperm<XOR1>(sp);
            sp += dpp_qperm<XOR2>(sp);
            const float s = sp + b2s + xv;

            if (r == 0) outv.x = s;
            else if (r == 1) outv.y = s;
            else if (r == 2) outv.z = s;
            else outv.w = s;
        }

        if (q == 0) ob4[gb] = outv;
        xc = xn;
    }
}

extern "C" void kernel_launch(void* const* d_in, const int* in_sizes, int n_in,
                              void* d_out, int out_size, void* d_ws, size_t ws_size,
                              hipStream_t stream) {
    const float* x    = (const float*)d_in[0];
    const float* h0   = (const float*)d_in[1];
    const float* c0   = (const float*)d_in[2];
    const float* W_ih = (const float*)d_in[3];
    const float* W_hh = (const float*)d_in[4];
    const float* b_ih = (const float*)d_in[5];
    const float* b_hh = (const float*)d_in[6];
    const float* W1   = (const float*)d_in[7];
    const float* b1   = (const float*)d_in[8];
    const float* W2   = (const float*)d_in[9];
    const float* b2   = (const float*)d_in[10];
    float* out = (float*)d_out;

    dim3 grid(BB * 4 / 64);   // 256 blocks: one wave per CU
    dim3 block(64);
    lstm_quad_dpp_kernel<<<grid, block, 0, stream>>>(x, h0, c0, W_ih, W_hh, b_ih, b_hh,
                                                     W1, b1, W2, b2, out);
}

// Round 8
// 189.167 us; speedup vs baseline: 1.4871x; 1.4871x over previous
//
#include <hip/hip_runtime.h>

#define BB 4096
#define TT 512
#define HH 10
#define L2E 1.44269504088896340736f

typedef __fp16 half2_t __attribute__((ext_vector_type(2)));

__device__ __forceinline__ float rcp_(float x) { return __builtin_amdgcn_rcpf(x); }
__device__ __forceinline__ float exp2_(float x) { return __builtin_amdgcn_exp2f(x); }

// ds_swizzle BitMode: src_lane = ((lane & and) | or) ^ xor ; offset = xor<<10 | or<<5 | and
#define SWZ(v, off) __int_as_float(__builtin_amdgcn_ds_swizzle(__float_as_int(v), (off)))
#define BPERM(idx, v) __int_as_float(__builtin_amdgcn_ds_bpermute((idx), __float_as_int(v)))

// 8 lanes per batch element. Lane l holds gate-rows r = 8m + l (m=0..4), perfectly
// balanced 5 rows/lane (rows 0..39 in torch i,f,g,o order). Activation applied at the
// holder as sigma(z*mult) with mult = log2e (sigmoid rows) or 2*log2e (tanh rows,
// recovered as 2*sigma-1 at the consumer). Unit u owned by lane u%8 (lanes 0,1 also
// own units 8,9). Gathers via 6 ds_bpermute rotations; h all-gather via 10 ds_swizzle
// broadcasts; weights f16-packed for v_dot2_f32_f16 so everything fits < 128 VGPRs.
__global__ __launch_bounds__(64) void lstm8_kernel(
    const float* __restrict__ x, const float* __restrict__ h0, const float* __restrict__ c0,
    const float* __restrict__ W_ih, const float* __restrict__ W_hh,
    const float* __restrict__ b_ih, const float* __restrict__ b_hh,
    const float* __restrict__ W1, const float* __restrict__ b1,
    const float* __restrict__ W2, const float* __restrict__ b2,
    float* __restrict__ out)
{
    const int lane = threadIdx.x;          // block = 64 = one wave = 8 elements
    const int l = lane & 7;                // lane within 8-lane group
    const int e = blockIdx.x * 8 + (lane >> 3);

    // ---- per-lane weights (f16-packed) ----
    half2_t Wp[5][5];                      // rows 8m+l of W_hh, 5 f16-pairs each
    float brow[5], wihr[5], mult[5];
#pragma unroll
    for (int m = 0; m < 5; m++) {
        const int r = 8 * m + l;
        const float2* rp = (const float2*)(W_hh + r * HH);   // 40B row stride, 8B aligned
#pragma unroll
        for (int p = 0; p < 5; p++) {
            float2 w = rp[p];
            Wp[m][p] = __builtin_amdgcn_cvt_pkrtz(w.x, w.y);
        }
        brow[m] = b_ih[r] + b_hh[r];
        wihr[m] = W_ih[r];
        mult[m] = (r >= 20 && r < 30) ? 2.0f * L2E : L2E;    // rows 20..29 are g (tanh)
    }
    const bool v2 = (l < 2);
    const int u1 = l, u2 = 8 + l;
    half2_t W1p1[5], W1p2[5];
    float b1r1, b1r2, W2r1, W2r2;
    {
        const float2* rp = (const float2*)(W1 + u1 * HH);
#pragma unroll
        for (int p = 0; p < 5; p++) { float2 w = rp[p]; W1p1[p] = __builtin_amdgcn_cvt_pkrtz(w.x, w.y); }
        b1r1 = b1[u1]; W2r1 = W2[u1];
        const float2* rp2 = (const float2*)(W1 + (v2 ? u2 : u1) * HH);
#pragma unroll
        for (int p = 0; p < 5; p++) {
            float2 w = rp2[p];
            W1p2[p] = __builtin_amdgcn_cvt_pkrtz(v2 ? w.x : 0.0f, v2 ? w.y : 0.0f);
        }
        b1r2 = v2 ? b1[u2] : 0.0f;
        W2r2 = v2 ? W2[u2] : 0.0f;
    }
    const float b2s = b2[0];

    // ---- bpermute rotation indices (byte addresses, group-local rotate) ----
    const int gbase = lane & ~7;
    const int rot2 = 4 * (gbase | ((l + 2) & 7));
    const int rot4 = 4 * (gbase | ((l + 4) & 7));
    const int rot6 = 4 * (gbase | ((l + 6) & 7));

    // ---- state ----
    float c1 = c0[e * HH + u1];
    float c2 = v2 ? c0[e * HH + u2] : 0.0f;
    float hb[10];
#pragma unroll
    for (int j = 0; j < 10; j++) hb[j] = h0[e * HH + j];
    half2_t hp[5];
#pragma unroll
    for (int p = 0; p < 5; p++) hp[p] = __builtin_amdgcn_cvt_pkrtz(hb[2 * p], hb[2 * p + 1]);

    const float4* xq  = (const float4*)(x + (size_t)e * TT);
    float4*       ob4 = (float4*)(out + (size_t)e * TT);

    float4 xc = xq[0];
    for (int gb = 0; gb < TT / 4; gb++) {
        float4 xn = xq[(gb + 1 < TT / 4) ? gb + 1 : gb];
        float4 outv;

#pragma unroll
        for (int r4 = 0; r4 < 4; r4++) {
            const float xv = (r4 == 0) ? xc.x : (r4 == 1) ? xc.y : (r4 == 2) ? xc.z : xc.w;

            // ---- 5 gate-rows: bias + x*wih + h.W via dot2, then unified sigma ----
            float act[5];
#pragma unroll
            for (int m = 0; m < 5; m++) {
                float g = fmaf(xv, wihr[m], brow[m]);
#pragma unroll
                for (int p = 0; p < 5; p++)
                    g = __builtin_amdgcn_fdot2(hp[p], Wp[m][p], g, false);
                act[m] = rcp_(1.0f + exp2_(-g * mult[m]));   // sigma; tanh rows hold sigma(2z)
            }

            // ---- gather gates to unit owners (rows u, 10+u, 20+u, 30+u) ----
            float b1_ = BPERM(rot2, act[1]);
            float b2a = BPERM(rot2, act[2]);
            float b2b = BPERM(rot4, act[2]);
            float b3a = BPERM(rot4, act[3]);
            float b3b = BPERM(rot6, act[3]);
            float b4  = BPERM(rot6, act[4]);
            const float i1 = act[0];                 // row l        (local)
            const float f1v = (l < 6) ? b1_ : b2a;   // row 10+l
            const float g1v = (l < 4) ? b2b : b3a;   // row 20+l  (= sigma(2z))
            const float o1v = (l < 2) ? b3b : b4;    // row 30+l
            const float i2 = act[1];                 // row 8+l      (local, lanes 0,1)
            const float f2v = b2a;                   // row 18+l
            const float g2v = b3a;                   // row 28+l
            const float o2v = b4;                    // row 38+l

            // ---- c/h update: tanh(z) = 2*sigma(2z)-1 folded into consumers ----
            float p1 = i1 * g1v;
            float cn1 = fmaf(f1v, c1, fmaf(2.0f, p1, -i1));
            c1 = cn1;
            float t1 = rcp_(1.0f + exp2_(cn1 * (-2.0f * L2E)));
            float h1 = o1v * fmaf(2.0f, t1, -1.0f);
            float p2 = i2 * g2v;
            float cn2 = fmaf(f2v, c2, fmaf(2.0f, p2, -i2));
            c2 = cn2;
            float t2 = rcp_(1.0f + exp2_(cn2 * (-2.0f * L2E)));
            float h2 = o2v * fmaf(2.0f, t2, -1.0f);

            // ---- broadcast h to all 8 lanes of the group (ds_swizzle, and=0x18,or=u) ----
            hb[0] = SWZ(h1, 0x18); hb[1] = SWZ(h1, 0x38);
            hb[2] = SWZ(h1, 0x58); hb[3] = SWZ(h1, 0x78);
            hb[4] = SWZ(h1, 0x98); hb[5] = SWZ(h1, 0xB8);
            hb[6] = SWZ(h1, 0xD8); hb[7] = SWZ(h1, 0xF8);
            hb[8] = SWZ(h2, 0x18); hb[9] = SWZ(h2, 0x38);

#pragma unroll
            for (int p = 0; p < 5; p++)
                hp[p] = __builtin_amdgcn_cvt_pkrtz(hb[2 * p], hb[2 * p + 1]);

            // ---- regressor: relu(W1 h + b1) . W2, 8-lane xor reduce (off critical path) ----
            float a1 = b1r1, a2 = b1r2;
#pragma unroll
            for (int p = 0; p < 5; p++) {
                a1 = __builtin_amdgcn_fdot2(hp[p], W1p1[p], a1, false);
                a2 = __builtin_amdgcn_fdot2(hp[p], W1p2[p], a2, false);
            }
            float part = fmaf(fmaxf(a1, 0.0f), W2r1, fmaxf(a2, 0.0f) * W2r2);
            part += SWZ(part, 0x041F);   // xor 1
            part += SWZ(part, 0x081F);   // xor 2
            part += SWZ(part, 0x101F);   // xor 4
            const float s = part + b2s + xv;

            if (r4 == 0) outv.x = s;
            else if (r4 == 1) outv.y = s;
            else if (r4 == 2) outv.z = s;
            else outv.w = s;
        }

        if (l == 0) ob4[gb] = outv;
        xc = xn;
    }
}

extern "C" void kernel_launch(void* const* d_in, const int* in_sizes, int n_in,
                              void* d_out, int out_size, void* d_ws, size_t ws_size,
                              hipStream_t stream) {
    const float* x    = (const float*)d_in[0];
    const float* h0   = (const float*)d_in[1];
    const float* c0   = (const float*)d_in[2];
    const float* W_ih = (const float*)d_in[3];
    const float* W_hh = (const float*)d_in[4];
    const float* b_ih = (const float*)d_in[5];
    const float* b_hh = (const float*)d_in[6];
    const float* W1   = (const float*)d_in[7];
    const float* b1   = (const float*)d_in[8];
    const float* W2   = (const float*)d_in[9];
    const float* b2   = (const float*)d_in[10];
    float* out = (float*)d_out;

    dim3 grid(BB * 8 / 64);   // 512 blocks: 2 waves per CU
    dim3 block(64);
    lstm8_kernel<<<grid, block, 0, stream>>>(x, h0, c0, W_ih, W_hh, b_ih, b_hh,
                                             W1, b1, W2, b2, out);
}

// Round 9
// 145.005 us; speedup vs baseline: 1.9401x; 1.3046x over previous
//
#include <hip/hip_runtime.h>

#define BB 4096
#define TT 512
#define HH 10
#define L2E 1.44269504088896340736f

typedef __fp16 half2_t __attribute__((ext_vector_type(2)));

__device__ __forceinline__ float rcp_(float x) { return __builtin_amdgcn_rcpf(x); }
__device__ __forceinline__ float exp2_(float x) { return __builtin_amdgcn_exp2f(x); }

// ds_swizzle BitMode: src_lane = ((lane & and) | or) ^ xor ; offset = xor<<10 | or<<5 | and
#define SWZ(v, off) __int_as_float(__builtin_amdgcn_ds_swizzle(__float_as_int(v), (off)))
#define BPERM(idx, v) __int_as_float(__builtin_amdgcn_ds_bpermute((idx), __float_as_int(v)))

// 16 lanes per batch element (4 elements per wave, 1024 blocks = 4 waves/CU).
// Lane l holds gate rows r0=l, r1=16+l, and r2=32+l for l<8 (torch i,f,g,o row order,
// 40 rows total). Row->register map is gate-homogeneous: a0 = act(r0) (i for l<10,
// f for l>=10), a1 = act(r1) (f for l<4, g for 4<=l<14, o for l>=14), a2 = act(r2)
// (o, lanes 0..7). Activations applied at the holder as sigma(z*mult); tanh rows use
// mult=2*log2e and are recovered as 2*sigma-1 at the consumer. Lane u<10 owns hidden
// unit u: gathers f/g/o with 3 ds_bpermute (precomputed indices; f/o pre-merged into
// one register with a cndmask), i is local. h all-gather: 10 ds_swizzle broadcasts.
// Weights f16-packed for v_dot2_f32_f16; everything register-resident (~70 VGPR).
__global__ __launch_bounds__(64) void lstm16_kernel(
    const float* __restrict__ x, const float* __restrict__ h0, const float* __restrict__ c0,
    const float* __restrict__ W_ih, const float* __restrict__ W_hh,
    const float* __restrict__ b_ih, const float* __restrict__ b_hh,
    const float* __restrict__ W1, const float* __restrict__ b1,
    const float* __restrict__ W2, const float* __restrict__ b2,
    float* __restrict__ out)
{
    const int lane = threadIdx.x;          // block = 64 = one wave = 4 elements
    const int l = lane & 15;               // lane within 16-lane group
    const int e = blockIdx.x * 4 + (lane >> 4);

    // ---- per-lane gate-row weights (f16-packed) ----
    const int r0 = l;
    const int r1 = 16 + l;
    const int r2 = (l < 8) ? 32 + l : 32;  // dummy (row 32) for l>=8; its act is never consumed
    half2_t Wp0[5], Wp1[5], Wp2[5];
    {
        const float2* p0 = (const float2*)(W_hh + r0 * HH);
        const float2* p1 = (const float2*)(W_hh + r1 * HH);
        const float2* p2 = (const float2*)(W_hh + r2 * HH);
#pragma unroll
        for (int p = 0; p < 5; p++) {
            float2 w0 = p0[p], w1 = p1[p], w2 = p2[p];
            Wp0[p] = __builtin_amdgcn_cvt_pkrtz(w0.x, w0.y);
            Wp1[p] = __builtin_amdgcn_cvt_pkrtz(w1.x, w1.y);
            Wp2[p] = __builtin_amdgcn_cvt_pkrtz(w2.x, w2.y);
        }
    }
    const float b0 = b_ih[r0] + b_hh[r0];
    const float b1_ = b_ih[r1] + b_hh[r1];
    const float b2_ = b_ih[r2] + b_hh[r2];
    const float wih0 = W_ih[r0], wih1 = W_ih[r1], wih2 = W_ih[r2];
    // negated exp2 multipliers: act = rcp(1 + exp2(g * negm))
    const float negm0 = -L2E;                                      // rows 0..15: i/f sigmoid
    const float negm1 = (r1 >= 20 && r1 < 30) ? -2.0f * L2E : -L2E; // g rows are tanh
    const float negm2 = -L2E;                                      // o rows sigmoid

    // ---- unit ownership (lane u < 10 owns unit u) ----
    const bool owner = (l < HH);
    const int u = owner ? l : 0;
    half2_t W1p[5];
    float b1r, W2r;
    {
        const float2* rp = (const float2*)(W1 + u * HH);
#pragma unroll
        for (int p = 0; p < 5; p++) {
            float2 w = rp[p];
            W1p[p] = __builtin_amdgcn_cvt_pkrtz(owner ? w.x : 0.0f, owner ? w.y : 0.0f);
        }
        b1r = owner ? b1[u] : 0.0f;
        W2r = owner ? W2[u] : 0.0f;
    }
    const float b2s = b2[0];

    // ---- precomputed bpermute byte-indices (full-wave lane addressing) ----
    const int gbase = lane & ~15;
    const int fidx = 4 * (gbase | ((u < 6) ? 10 + u : u - 6));  // row 10+u holder
    const int gidx = 4 * (gbase | (u + 4));                     // row 20+u holder (a1)
    const int oidx = 4 * (gbase | ((u < 2) ? 14 + u : u - 2));  // row 30+u holder

    // ---- state ----
    float c = owner ? c0[e * HH + u] : 0.0f;
    float hb[10];
#pragma unroll
    for (int j = 0; j < 10; j++) hb[j] = h0[e * HH + j];
    half2_t hp[5];
#pragma unroll
    for (int p = 0; p < 5; p++) hp[p] = __builtin_amdgcn_cvt_pkrtz(hb[2 * p], hb[2 * p + 1]);

    const float4* xq  = (const float4*)(x + (size_t)e * TT);
    float4*       ob4 = (float4*)(out + (size_t)e * TT);

    float4 xc = xq[0];
    for (int gb = 0; gb < TT / 4; gb++) {
        float4 xn = xq[(gb + 1 < TT / 4) ? gb + 1 : gb];
        float4 outv;

#pragma unroll
        for (int r4 = 0; r4 < 4; r4++) {
            const float xv = (r4 == 0) ? xc.x : (r4 == 1) ? xc.y : (r4 == 2) ? xc.z : xc.w;

            // ---- 2-3 gate rows: bias + x*wih + h.W via dot2, unified sigma ----
            float g0 = fmaf(xv, wih0, b0);
            float g1 = fmaf(xv, wih1, b1_);
            float g2 = fmaf(xv, wih2, b2_);
#pragma unroll
            for (int p = 0; p < 5; p++) {
                g0 = __builtin_amdgcn_fdot2(hp[p], Wp0[p], g0, false);
                g1 = __builtin_amdgcn_fdot2(hp[p], Wp1[p], g1, false);
                g2 = __builtin_amdgcn_fdot2(hp[p], Wp2[p], g2, false);
            }
            const float a0 = rcp_(1.0f + exp2_(g0 * negm0));
            const float a1 = rcp_(1.0f + exp2_(g1 * negm1));
            const float a2 = rcp_(1.0f + exp2_(g2 * negm2));

            // ---- gather gates to unit owners ----
            const float vf = (l >= 10) ? a0 : a1;   // f lives in a0 (lanes 10-15) or a1 (lanes 0-3)
            const float vo = (l >= 14) ? a1 : a2;   // o lives in a1 (lanes 14,15) or a2 (lanes 0-7)
            const float fv = BPERM(fidx, vf);
            const float gv = BPERM(gidx, a1);       // sigma(2z) of g-row
            const float ov = BPERM(oidx, vo);
            const float iv = a0;                    // own i-row (owner lanes)

            // ---- c/h update: tanh(z) = 2*sigma(2z)-1 folded in ----
            const float pg = iv * gv;
            const float cn = fmaf(fv, c, fmaf(2.0f, pg, -iv));
            c = cn;
            const float t = rcp_(1.0f + exp2_(cn * (-2.0f * L2E)));
            const float hq = ov * fmaf(2.0f, t, -1.0f);

            // ---- broadcast h to all 16 lanes (ds_swizzle and=0x10, or=u) ----
            hb[0] = SWZ(hq, 0x010); hb[1] = SWZ(hq, 0x030);
            hb[2] = SWZ(hq, 0x050); hb[3] = SWZ(hq, 0x070);
            hb[4] = SWZ(hq, 0x090); hb[5] = SWZ(hq, 0x0B0);
            hb[6] = SWZ(hq, 0x0D0); hb[7] = SWZ(hq, 0x0F0);
            hb[8] = SWZ(hq, 0x110); hb[9] = SWZ(hq, 0x130);
#pragma unroll
            for (int p = 0; p < 5; p++)
                hp[p] = __builtin_amdgcn_cvt_pkrtz(hb[2 * p], hb[2 * p + 1]);

            // ---- regressor: owner lane u computes relu(W1_u.h + b1_u)*W2_u, 16-lane reduce ----
            float a = b1r;
#pragma unroll
            for (int p = 0; p < 5; p++)
                a = __builtin_amdgcn_fdot2(hp[p], W1p[p], a, false);
            float part = fmaxf(a, 0.0f) * W2r;
            part += SWZ(part, 0x041F);   // xor 1
            part += SWZ(part, 0x081F);   // xor 2
            part += SWZ(part, 0x101F);   // xor 4
            part += SWZ(part, 0x201F);   // xor 8
            const float s = part + b2s + xv;

            if (r4 == 0) outv.x = s;
            else if (r4 == 1) outv.y = s;
            else if (r4 == 2) outv.z = s;
            else outv.w = s;
        }

        if (l == 0) ob4[gb] = outv;
        xc = xn;
    }
}

extern "C" void kernel_launch(void* const* d_in, const int* in_sizes, int n_in,
                              void* d_out, int out_size, void* d_ws, size_t ws_size,
                              hipStream_t stream) {
    const float* x    = (const float*)d_in[0];
    const float* h0   = (const float*)d_in[1];
    const float* c0   = (const float*)d_in[2];
    const float* W_ih = (const float*)d_in[3];
    const float* W_hh = (const float*)d_in[4];
    const float* b_ih = (const float*)d_in[5];
    const float* b_hh = (const float*)d_in[6];
    const float* W1   = (const float*)d_in[7];
    const float* b1   = (const float*)d_in[8];
    const float* W2   = (const float*)d_in[9];
    const float* b2   = (const float*)d_in[10];
    float* out = (float*)d_out;

    dim3 grid(BB * 16 / 64);   // 1024 blocks: 4 waves/CU (1 per SIMD)
    dim3 block(64);
    lstm16_kernel<<<grid, block, 0, stream>>>(x, h0, c0, W_ih, W_hh, b_ih, b_hh,
                                              W1, b1, W2, b2, out);
}

// Round 10
// 126.693 us; speedup vs baseline: 2.2205x; 1.1445x over previous
//
#include <hip/hip_runtime.h>

#define BB 4096
#define TT 512
#define HH 10
#define L2E 1.44269504088896340736f

typedef __fp16 half2_t __attribute__((ext_vector_type(2)));

__device__ __forceinline__ float rcp_(float x) { return __builtin_amdgcn_rcpf(x); }
__device__ __forceinline__ float exp2_(float x) { return __builtin_amdgcn_exp2f(x); }

// ds_swizzle BitMode (per 32-lane half): src = ((lane & and) | or) ^ xor ;
// offset = xor<<10 | or<<5 | and. Broadcast unit-owner j to its 16-group: and=0x10, or=j.
#define SWZ(v, off) __int_as_float(__builtin_amdgcn_ds_swizzle(__float_as_int(v), (off)))

// DPP: quad_perm (0x00-0xFF) and row_ror:N (0x120|N, rotate within 16-lane row).
template <int CTRL>
__device__ __forceinline__ float dpp_(float v) {
    return __int_as_float(__builtin_amdgcn_update_dpp(
        0, __float_as_int(v), CTRL, 0xf, 0xf, true));
}
#define QP_XOR1 0xB1   // [1,0,3,2]
#define QP_XOR2 0x4E   // [2,3,0,1]
#define ROR4    0x124
#define ROR8    0x128

// 16 lanes per batch element (4 elements/wave, 1024 waves = 1/SIMD chip-wide).
// Owner lane u<10 holds ALL FOUR gate rows of its unit {u,10+u,20+u,30+u} (f16-packed
// for v_dot2_f32_f16), so i,f,g,o are lane-local: no gate gather. tanh rows evaluated
// as sigma(2z), recovered via 2s-1. Per step the only LDS-pipe episode is the
// 10-swizzle h-broadcast; the regressor 16-lane reduce is pure DPP (quad_perm xor1,
// xor2, row_ror:4, row_ror:8). Lanes 10-15 carry zeroed weights (their lanes
// contribute 0 to the reduce and are never read by the broadcast).
__global__ __launch_bounds__(64) void lstm16o_kernel(
    const float* __restrict__ x, const float* __restrict__ h0, const float* __restrict__ c0,
    const float* __restrict__ W_ih, const float* __restrict__ W_hh,
    const float* __restrict__ b_ih, const float* __restrict__ b_hh,
    const float* __restrict__ W1, const float* __restrict__ b1,
    const float* __restrict__ W2, const float* __restrict__ b2,
    float* __restrict__ out)
{
    const int lane = threadIdx.x;          // block = 64 = one wave = 4 elements
    const int l = lane & 15;               // lane within 16-lane group
    const int e = blockIdx.x * 4 + (lane >> 4);

    const bool owner = (l < HH);
    const int u = owner ? l : 0;
    const float m = owner ? 1.0f : 0.0f;

    // ---- per-lane weights: all 4 gate rows of unit u (f16-packed) ----
    const int ri = u, rf = 10 + u, rg = 20 + u, ro = 30 + u;
    half2_t Wi[5], Wf[5], Wg[5], Wo[5];
    {
        const float2* pi = (const float2*)(W_hh + ri * HH);
        const float2* pf = (const float2*)(W_hh + rf * HH);
        const float2* pg = (const float2*)(W_hh + rg * HH);
        const float2* po = (const float2*)(W_hh + ro * HH);
#pragma unroll
        for (int p = 0; p < 5; p++) {
            float2 wi = pi[p], wf = pf[p], wg = pg[p], wo = po[p];
            Wi[p] = __builtin_amdgcn_cvt_pkrtz(wi.x * m, wi.y * m);
            Wf[p] = __builtin_amdgcn_cvt_pkrtz(wf.x * m, wf.y * m);
            Wg[p] = __builtin_amdgcn_cvt_pkrtz(wg.x * m, wg.y * m);
            Wo[p] = __builtin_amdgcn_cvt_pkrtz(wo.x * m, wo.y * m);
        }
    }
    const float bi = b_ih[ri] + b_hh[ri];
    const float bf = b_ih[rf] + b_hh[rf];
    const float bg = b_ih[rg] + b_hh[rg];
    const float bo = b_ih[ro] + b_hh[ro];
    const float wii = W_ih[ri], wif = W_ih[rf], wig = W_ih[rg], wio = W_ih[ro];

    // ---- regressor row u ----
    half2_t W1p[5];
    {
        const float2* rp = (const float2*)(W1 + u * HH);
#pragma unroll
        for (int p = 0; p < 5; p++) {
            float2 w = rp[p];
            W1p[p] = __builtin_amdgcn_cvt_pkrtz(w.x * m, w.y * m);
        }
    }
    const float b1r = m * b1[u];
    const float W2r = m * W2[u];
    const float b2s = b2[0];

    // ---- state ----
    float c = owner ? c0[e * HH + u] : 0.0f;
    float hb[10];
#pragma unroll
    for (int j = 0; j < 10; j++) hb[j] = h0[e * HH + j];
    half2_t hp[5];
#pragma unroll
    for (int p = 0; p < 5; p++) hp[p] = __builtin_amdgcn_cvt_pkrtz(hb[2 * p], hb[2 * p + 1]);

    const float4* xq  = (const float4*)(x + (size_t)e * TT);
    float4*       ob4 = (float4*)(out + (size_t)e * TT);

    float4 xc = xq[0];
    for (int gb = 0; gb < TT / 4; gb++) {
        float4 xn = xq[(gb + 1 < TT / 4) ? gb + 1 : gb];
        float4 outv;

#pragma unroll
        for (int r4 = 0; r4 < 4; r4++) {
            const float xv = (r4 == 0) ? xc.x : (r4 == 1) ? xc.y : (r4 == 2) ? xc.z : xc.w;

            // ---- 4 lane-local gate rows: bias + x*wih + h.W via dot2 ----
            float gi = fmaf(xv, wii, bi);
            float gf = fmaf(xv, wif, bf);
            float gg = fmaf(xv, wig, bg);
            float go = fmaf(xv, wio, bo);
#pragma unroll
            for (int p = 0; p < 5; p++) {
                gi = __builtin_amdgcn_fdot2(hp[p], Wi[p], gi, false);
                gf = __builtin_amdgcn_fdot2(hp[p], Wf[p], gf, false);
                gg = __builtin_amdgcn_fdot2(hp[p], Wg[p], gg, false);
                go = __builtin_amdgcn_fdot2(hp[p], Wo[p], go, false);
            }
            const float ai = rcp_(1.0f + exp2_(gi * (-L2E)));
            const float af = rcp_(1.0f + exp2_(gf * (-L2E)));
            const float ag = rcp_(1.0f + exp2_(gg * (-2.0f * L2E)));  // sigma(2z)
            const float ao = rcp_(1.0f + exp2_(go * (-L2E)));

            // ---- c/h update: tanh(z) = 2*sigma(2z)-1 folded in ----
            const float pg = ai * ag;
            const float cn = fmaf(af, c, fmaf(2.0f, pg, -ai));
            c = cn;
            const float t = rcp_(1.0f + exp2_(cn * (-2.0f * L2E)));
            const float hq = ao * fmaf(2.0f, t, -1.0f);

            // ---- ONE LDS episode: broadcast h_u from owner lanes to the 16-group ----
            hb[0] = SWZ(hq, 0x010); hb[1] = SWZ(hq, 0x030);
            hb[2] = SWZ(hq, 0x050); hb[3] = SWZ(hq, 0x070);
            hb[4] = SWZ(hq, 0x090); hb[5] = SWZ(hq, 0x0B0);
            hb[6] = SWZ(hq, 0x0D0); hb[7] = SWZ(hq, 0x0F0);
            hb[8] = SWZ(hq, 0x110); hb[9] = SWZ(hq, 0x130);
#pragma unroll
            for (int p = 0; p < 5; p++)
                hp[p] = __builtin_amdgcn_cvt_pkrtz(hb[2 * p], hb[2 * p + 1]);

            // ---- regressor: relu(W1_u.h + b1_u)*W2_u, 16-lane reduce in pure DPP ----
            float a = b1r;
#pragma unroll
            for (int p = 0; p < 5; p++)
                a = __builtin_amdgcn_fdot2(hp[p], W1p[p], a, false);
            float part = fmaxf(a, 0.0f) * W2r;
            part += dpp_<QP_XOR1>(part);   // quad pairs
            part += dpp_<QP_XOR2>(part);   // quad sums
            part += dpp_<ROR4>(part);      // adjacent-quad sums
            part += dpp_<ROR8>(part);      // full 16-lane sum (all lanes)
            const float s = part + b2s + xv;

            if (r4 == 0) outv.x = s;
            else if (r4 == 1) outv.y = s;
            else if (r4 == 2) outv.z = s;
            else outv.w = s;
        }

        if (l == 0) ob4[gb] = outv;
        xc = xn;
    }
}

extern "C" void kernel_launch(void* const* d_in, const int* in_sizes, int n_in,
                              void* d_out, int out_size, void* d_ws, size_t ws_size,
                              hipStream_t stream) {
    const float* x    = (const float*)d_in[0];
    const float* h0   = (const float*)d_in[1];
    const float* c0   = (const float*)d_in[2];
    const float* W_ih = (const float*)d_in[3];
    const float* W_hh = (const float*)d_in[4];
    const float* b_ih = (const float*)d_in[5];
    const float* b_hh = (const float*)d_in[6];
    const float* W1   = (const float*)d_in[7];
    const float* b1   = (const float*)d_in[8];
    const float* W2   = (const float*)d_in[9];
    const float* b2   = (const float*)d_in[10];
    float* out = (float*)d_out;

    dim3 grid(BB * 16 / 64);   // 1024 blocks: 4 waves/CU (1 per SIMD)
    dim3 block(64);
    lstm16o_kernel<<<grid, block, 0, stream>>>(x, h0, c0, W_ih, W_hh, b_ih, b_hh,
                                               W1, b1, W2, b2, out);
}